// Round 13
// baseline (60.458 us; speedup 1.0000x reference)
//
#include <hip/hip_runtime.h>

#define T_DIM 1024
#define B_DIM 4
#define D_DIM 512
#define DQ (D_DIM / 4)                 // 128 float4 per row
#define NROWS (T_DIM * B_DIM)
#define SSTR ((size_t)NROWS * 4 * DQ)  // scale-slab stride in float4 units

// ---------------- Kernel 1: per-(b,t) inverse L2 norm over D ----------------
__global__ __launch_bounds__(256) void norm_kernel(const float* __restrict__ x,
                                                   float* __restrict__ inv) {
    const int wave = threadIdx.x >> 6;
    const int lane = threadIdx.x & 63;
    const int row  = blockIdx.x * 4 + wave;          // grid = NROWS/4 exactly
    const float4* xr = reinterpret_cast<const float4*>(x) + (size_t)row * DQ;
    float4 a = xr[lane];
    float4 c = xr[lane + 64];
    float s2 = a.x*a.x + a.y*a.y + a.z*a.z + a.w*a.w
             + c.x*c.x + c.y*c.y + c.z*c.z + c.w*c.w;
    #pragma unroll
    for (int off = 32; off > 0; off >>= 1) s2 += __shfl_xor(s2, off, 64);
    if (lane == 0) inv[row] = 1.0f / fmaxf(sqrtf(s2), 1e-12f);
}

// ---------------- Kernel 2: wave-specialized producer/consumer --------------
// Waves 0-1 (128 threads): compute acc[16] for one output row n (loads + FMA
// ONLY — no store ever enters their vm stream), hand off via 32 KB LDS.
// Wave 2 (64 threads): PURE-STORE wave — drains LDS to global as a
// fillBuffer-like store-only instruction stream.
__device__ __forceinline__ void fma4(float4& a, float wt, const float4& v) {
    a.x += wt * v.x; a.y += wt * v.y; a.z += wt * v.z; a.w += wt * v.w;
}

template<int S>
__device__ __forceinline__ void gen_scale(const float* __restrict__ W,
                                          const float4* __restrict__ xq,
                                          const float* __restrict__ inv,
                                          int j, int b,
                                          float4* acc) {   // acc[0..3]
    const int lo = max(0, j - S / 2 + 1);
    const int hi = min(j + S / 2, T_DIM - 1);
    for (int t = lo; t <= hi; ++t) {
        float4 xv = xq[(size_t)t * DQ];
        const float s = inv[b * T_DIM + t];
        xv.x *= s; xv.y *= s; xv.z *= s; xv.w *= s;
        const int kk = t - lo;
        fma4(acc[0], W[0 * S + kk], xv);
        fma4(acc[1], W[1 * S + kk], xv);
        fma4(acc[2], W[2 * S + kk], xv);
        fma4(acc[3], W[3 * S + kk], xv);
    }
}

__global__ __launch_bounds__(192) void pool_kernel(const float* __restrict__ x,
                                                   const float* __restrict__ inv,
                                                   const float* __restrict__ W0,
                                                   const float* __restrict__ W1,
                                                   const float* __restrict__ W2,
                                                   const float* __restrict__ W3,
                                                   float* __restrict__ out) {
    __shared__ float4 lbuf[16 * 128];                // 32 KB handoff buffer
    // XCD-chunked bijective map: XCD k handles 512 consecutive n.
    const int n = (blockIdx.x & 7) * (NROWS / 8) + (blockIdx.x >> 3);
    const int j = n >> 2;                            // n = j*B + b (ref order)
    const int b = n & 3;
    const int tid = threadIdx.x;

    if (tid < 128) {
        // -------- compute waves (vm stream: loads only) --------
        const int q = tid;
        const float4* xq   = reinterpret_cast<const float4*>(x) + (size_t)b * T_DIM * DQ + q;
        const float*  invb = inv + b * T_DIM;

        float4 acc[16];                              // [si*4 + o]
        #pragma unroll
        for (int i = 0; i < 16; ++i) acc[i] = make_float4(0.f, 0.f, 0.f, 0.f);

        if (j >= 15 && j <= T_DIM - 17) {
            const int t0 = j - 15;
            #pragma unroll
            for (int k = 0; k < 32; ++k) {
                float4 xv = xq[(size_t)(t0 + k) * DQ];
                const float s = invb[t0 + k];        // uniform -> s_load
                xv.x *= s; xv.y *= s; xv.z *= s; xv.w *= s;
                if (k >= 14 && k < 18) {             // scale 4, base 14
                    #pragma unroll
                    for (int o = 0; o < 4; ++o) fma4(acc[0 + o], W0[o * 4 + (k - 14)], xv);
                }
                if (k >= 12 && k < 20) {             // scale 8, base 12
                    #pragma unroll
                    for (int o = 0; o < 4; ++o) fma4(acc[4 + o], W1[o * 8 + (k - 12)], xv);
                }
                if (k >= 8 && k < 24) {              // scale 16, base 8
                    #pragma unroll
                    for (int o = 0; o < 4; ++o) fma4(acc[8 + o], W2[o * 16 + (k - 8)], xv);
                }
                {                                    // scale 32, base 0
                    #pragma unroll
                    for (int o = 0; o < 4; ++o) fma4(acc[12 + o], W3[o * 32 + k], xv);
                }
            }
        } else {
            // Edge rows (124 of 4096 blocks): verified masked/shifted path.
            gen_scale<4 >(W0, xq, inv, j, b, &acc[0]);
            gen_scale<8 >(W1, xq, inv, j, b, &acc[4]);
            gen_scale<16>(W2, xq, inv, j, b, &acc[8]);
            gen_scale<32>(W3, xq, inv, j, b, &acc[12]);
        }

        #pragma unroll
        for (int i = 0; i < 16; ++i)
            lbuf[i * 128 + q] = acc[i];
    }

    __syncthreads();                                 // all 3 waves participate

    if (tid >= 128) {
        // -------- pure-store wave (vm stream: stores only) --------
        const int lane = tid - 128;                  // 0..63
        float4* outbase = reinterpret_cast<float4*>(out);
        const size_t nbase = (size_t)n * 4 * DQ;
        #pragma unroll
        for (int it = 0; it < 32; ++it) {
            const int f  = it * 64 + lane;           // 0..2047 over 16x128
            const int si = f >> 9;
            const int o  = (f >> 7) & 3;
            const int q  = f & 127;
            outbase[(size_t)si * SSTR + nbase + (size_t)o * DQ + q] = lbuf[f];
        }
    }
}

extern "C" void kernel_launch(void* const* d_in, const int* in_sizes, int n_in,
                              void* d_out, int out_size, void* d_ws, size_t ws_size,
                              hipStream_t stream) {
    const float* x  = (const float*)d_in[0];
    const float* W0 = (const float*)d_in[1];
    const float* W1 = (const float*)d_in[2];
    const float* W2 = (const float*)d_in[3];
    const float* W3 = (const float*)d_in[4];
    float* out = (float*)d_out;
    float* inv = (float*)d_ws;   // NROWS floats = 16 KB scratch

    norm_kernel<<<NROWS / 4, 256, 0, stream>>>(x, inv);
    pool_kernel<<<NROWS, 192, 0, stream>>>(x, inv, W0, W1, W2, W3, out);
}

// Round 14
// 41.458 us; speedup vs baseline: 1.4583x; 1.4583x over previous
//
#include <hip/hip_runtime.h>

#define T_DIM 1024
#define B_DIM 4
#define D_DIM 512
#define DQ (D_DIM / 4)                 // 128 float4 per row
#define NROWS (T_DIM * B_DIM)
#define SSTR ((size_t)NROWS * 4 * DQ)  // scale-slab stride in float4 units

// ---------------- Kernel 1: per-(b,t) inverse L2 norm over D ----------------
__global__ __launch_bounds__(256) void norm_kernel(const float* __restrict__ x,
                                                   float* __restrict__ inv) {
    const int wave = threadIdx.x >> 6;
    const int lane = threadIdx.x & 63;
    const int row  = blockIdx.x * 4 + wave;          // grid = NROWS/4 exactly
    const float4* xr = reinterpret_cast<const float4*>(x) + (size_t)row * DQ;
    float4 a = xr[lane];
    float4 c = xr[lane + 64];
    float s2 = a.x*a.x + a.y*a.y + a.z*a.z + a.w*a.w
             + c.x*c.x + c.y*c.y + c.z*c.z + c.w*c.w;
    #pragma unroll
    for (int off = 32; off > 0; off >>= 1) s2 += __shfl_xor(s2, off, 64);
    if (lane == 0) inv[row] = 1.0f / fmaxf(sqrtf(s2), 1e-12f);
}

// ---------------- Kernel 2: one output row n per block, TERMINAL stores -----
// Best verified structure (R11, 41.3 us): within a wave, NO load is ever
// issued after a store, so the shared in-order vmcnt counter never couples
// compute to store retirement. One streamed 32-row window feeds all 4 scales;
// single 16-store terminal burst. Writes run at ~3.5 TB/s — the empirical
// ceiling for compute-bearing shaders on this chip (D2D copy: 3.15 TB/s/dir).
__device__ __forceinline__ void fma4(float4& a, float wt, const float4& v) {
    a.x += wt * v.x; a.y += wt * v.y; a.z += wt * v.z; a.w += wt * v.w;
}

template<int S>
__device__ __forceinline__ void gen_scale(const float* __restrict__ W,
                                          const float4* __restrict__ xq,
                                          const float* __restrict__ inv,
                                          int j, int b,
                                          float4* acc) {   // acc[0..3]
    const int lo = max(0, j - S / 2 + 1);
    const int hi = min(j + S / 2, T_DIM - 1);
    for (int t = lo; t <= hi; ++t) {
        float4 xv = xq[(size_t)t * DQ];
        const float s = inv[b * T_DIM + t];
        xv.x *= s; xv.y *= s; xv.z *= s; xv.w *= s;
        const int kk = t - lo;
        fma4(acc[0], W[0 * S + kk], xv);
        fma4(acc[1], W[1 * S + kk], xv);
        fma4(acc[2], W[2 * S + kk], xv);
        fma4(acc[3], W[3 * S + kk], xv);
    }
}

__global__ __launch_bounds__(128) void pool_kernel(const float* __restrict__ x,
                                                   const float* __restrict__ inv,
                                                   const float* __restrict__ W0,
                                                   const float* __restrict__ W1,
                                                   const float* __restrict__ W2,
                                                   const float* __restrict__ W3,
                                                   float* __restrict__ out) {
    // XCD-chunked bijective map: XCD k handles 512 consecutive n.
    const int n = (blockIdx.x & 7) * (NROWS / 8) + (blockIdx.x >> 3);
    const int j = n >> 2;                            // n = j*B + b (ref order)
    const int b = n & 3;
    const int q = threadIdx.x;                       // one float4-quad per thread
    const float4* xq   = reinterpret_cast<const float4*>(x) + (size_t)b * T_DIM * DQ + q;
    const float*  invb = inv + b * T_DIM;

    float4 acc[16];                                  // [si*4 + o], compile-time idx
    #pragma unroll
    for (int i = 0; i < 16; ++i) acc[i] = make_float4(0.f, 0.f, 0.f, 0.f);

    if (j >= 15 && j <= T_DIM - 17) {
        // Interior: stream the 32-row window once, feed all 4 scales.
        const int t0 = j - 15;
        #pragma unroll
        for (int k = 0; k < 32; ++k) {
            float4 xv = xq[(size_t)(t0 + k) * DQ];
            const float s = invb[t0 + k];            // uniform -> s_load
            xv.x *= s; xv.y *= s; xv.z *= s; xv.w *= s;
            if (k >= 14 && k < 18) {                 // scale 4, base 14
                #pragma unroll
                for (int o = 0; o < 4; ++o) fma4(acc[0 + o], W0[o * 4 + (k - 14)], xv);
            }
            if (k >= 12 && k < 20) {                 // scale 8, base 12
                #pragma unroll
                for (int o = 0; o < 4; ++o) fma4(acc[4 + o], W1[o * 8 + (k - 12)], xv);
            }
            if (k >= 8 && k < 24) {                  // scale 16, base 8
                #pragma unroll
                for (int o = 0; o < 4; ++o) fma4(acc[8 + o], W2[o * 16 + (k - 8)], xv);
            }
            {                                        // scale 32, base 0
                #pragma unroll
                for (int o = 0; o < 4; ++o) fma4(acc[12 + o], W3[o * 32 + k], xv);
            }
        }
    } else {
        // Edge rows (124 of 4096 blocks): verified masked/shifted path.
        gen_scale<4 >(W0, xq, inv, j, b, &acc[0]);
        gen_scale<8 >(W1, xq, inv, j, b, &acc[4]);
        gen_scale<16>(W2, xq, inv, j, b, &acc[8]);
        gen_scale<32>(W3, xq, inv, j, b, &acc[12]);
    }

    // Terminal store burst: nothing in this wave waits on these.
    float4* outq = reinterpret_cast<float4*>(out) + (size_t)n * 4 * DQ + q;
    #pragma unroll
    for (int si = 0; si < 4; ++si)
        #pragma unroll
        for (int o = 0; o < 4; ++o)
            outq[(size_t)si * SSTR + (size_t)o * DQ] = acc[si * 4 + o];
}

extern "C" void kernel_launch(void* const* d_in, const int* in_sizes, int n_in,
                              void* d_out, int out_size, void* d_ws, size_t ws_size,
                              hipStream_t stream) {
    const float* x  = (const float*)d_in[0];
    const float* W0 = (const float*)d_in[1];
    const float* W1 = (const float*)d_in[2];
    const float* W2 = (const float*)d_in[3];
    const float* W3 = (const float*)d_in[4];
    float* out = (float*)d_out;
    float* inv = (float*)d_ws;   // NROWS floats = 16 KB scratch

    norm_kernel<<<NROWS / 4, 256, 0, stream>>>(x, inv);
    pool_kernel<<<NROWS, 128, 0, stream>>>(x, inv, W0, W1, W2, W3, out);
}